// Round 10
// baseline (1062.285 us; speedup 1.0000x reference)
//
#include <hip/hip_runtime.h>
#include <math.h>

#define BATCH     512
#define T_PAST_   360
#define T_FUT_    1800
#define IN_SZ     3
#define H_SZ      64
#define FUT_SEQ   50
#define WSPF_     34
#define MAX_STEPS (FUT_SEQ * WSPF_)      // 1700
#define T_TOT     (T_PAST_ + MAX_STEPS)  // 2060
#define NTHREADS  256
#define PSTRIDE   66                     // wproj row stride (2-way banks = free)

typedef __fp16 h2 __attribute__((ext_vector_type(2)));

__device__ __forceinline__ h2  as_h2(int v) { return __builtin_bit_cast(h2, v); }
__device__ __forceinline__ int as_i(h2 v)   { return __builtin_bit_cast(int, v); }

__device__ __forceinline__ float rcp_(float x) { return __builtin_amdgcn_rcpf(x); }

__device__ __forceinline__ float tanh_(float x) {
    float a = fabsf(x);
    float e = __expf(-2.0f * a);         // in (0,1], no overflow
    float t = (1.0f - e) * rcp_(1.0f + e);
    return copysignf(t, x);
}

// packed-pair dot with f32 accumulate: D = a.x*b.x + a.y*b.y + c
__device__ __forceinline__ float dot2_(int a, int b, float c) {
#if __has_builtin(__builtin_amdgcn_fdot2)
    return __builtin_amdgcn_fdot2(as_h2(a), as_h2(b), c, false);
#else
    h2 av = as_h2(a), bv = as_h2(b);
    return fmaf((float)av.x, (float)bv.x, fmaf((float)av.y, (float)bv.y, c));
#endif
}

__device__ __forceinline__ int rl_(int v, int src) {
    return __builtin_amdgcn_readlane(v, src);
}

// neighbor (lane^1) value via DPP quad_perm [1,0,3,2] — pure VALU, no LDS
__device__ __forceinline__ float dpp_xor1_(float v) {
    return __builtin_bit_cast(float,
        __builtin_amdgcn_update_dpp(0, __builtin_bit_cast(int, v),
                                    0xB1, 0xF, 0xF, true));
}

// 256 threads / 4 waves per batch element; thread = gate row. Weights: 32
// packed-fp16 VGPRs (pinned; r9 verified resident, VGPR_Count 68). The
// packed h-pair word `pk` stays in REGISTERS across steps: the dot reads it
// via v_readlane broadcasts, the lane^1 h for packing comes from DPP — the
// ~120-cyc LDS round-trip that sat on r9's recurrent critical path is gone.
// Per step the only LDS+barrier traffic is the unavoidable cross-wave gate
// exchange (double-buffered, one __syncthreads).
__global__ __launch_bounds__(NTHREADS, 2)
void lstm_fused_kernel(const float* __restrict__ wave_input,   // [B, 360, 3]
                       const float* __restrict__ wave_future,  // [B, 1800, 3]
                       const float* __restrict__ W_ih,         // [256, 3]
                       const float* __restrict__ W_hh,         // [256, 64]
                       const float* __restrict__ b_ih,         // [256]
                       const float* __restrict__ b_hh,         // [256]
                       const float* __restrict__ W_proj,       // [64, 64]
                       const float* __restrict__ b_proj,       // [64]
                       float* __restrict__ out)                // [B, 50, 64]
{
    __shared__ __align__(16) float x_lds[T_TOT * IN_SZ];       // 24.7 KB
    __shared__ __align__(16) float wproj_lds[H_SZ * PSTRIDE];  // 16.9 KB
    __shared__ __align__(16) float gates_lds[2][NTHREADS];     // 2 KB

    const int b    = blockIdx.x;
    const int tid  = threadIdx.x;      // gate row 0..255
    const int wv   = tid >> 6;
    const int lane = tid & 63;         // hidden unit this thread updates

    // ---- stage x sequence (coalesced, one-time) ----
    {
        const float* wi = wave_input + (size_t)b * (T_PAST_ * IN_SZ);
        for (int i = tid; i < T_PAST_ * IN_SZ; i += NTHREADS) x_lds[i] = wi[i];
        const float* wf = wave_future + (size_t)b * (T_FUT_ * IN_SZ);
        for (int i = tid; i < MAX_STEPS * IN_SZ; i += NTHREADS)
            x_lds[T_PAST_ * IN_SZ + i] = wf[i];
    }
    for (int i = tid; i < H_SZ * H_SZ; i += NTHREADS) {
        int r = i >> 6, cc = i & 63;
        wproj_lds[r * PSTRIDE + cc] = W_proj[i];
    }

    // ---- W_hh row `tid` as 32 packed fp16 pairs (32 VGPRs, pinned) ----
    int w2[32];
    {
        const float* rowp = W_hh + (size_t)tid * H_SZ;
        #pragma unroll
        for (int j = 0; j < 32; ++j)
            w2[j] = as_i(__builtin_amdgcn_cvt_pkrtz(rowp[2*j], rowp[2*j+1]));
    }
    #pragma unroll
    for (int k = 0; k < 32; k += 8)
        asm volatile("" : "+v"(w2[k+0]), "+v"(w2[k+1]), "+v"(w2[k+2]), "+v"(w2[k+3]),
                          "+v"(w2[k+4]), "+v"(w2[k+5]), "+v"(w2[k+6]), "+v"(w2[k+7]));

    const float wih0 = W_ih[tid * 3 + 0];
    const float wih1 = W_ih[tid * 3 + 1];
    const float wih2 = W_ih[tid * 3 + 2];
    const float bg   = b_ih[tid] + b_hh[tid];
    // unified activation: sigmoid for i,f,o; tanh(x) = 2*sigmoid(2x)-1 for g
    const bool  isg = (tid >= 2 * H_SZ) && (tid < 3 * H_SZ);
    const float sc  = isg ? 2.0f : 1.0f;
    const float aa  = isg ? 2.0f : 1.0f;
    const float bb  = isg ? -1.0f : 0.0f;
    const float bpj = b_proj[lane];

    float c = 0.0f;                    // unit `lane` state, per-wave copy
    int   pk = 0;                      // packed (h_2j, h_2j+1), valid on even lanes
    float* outb = out + (size_t)b * (FUT_SEQ * H_SZ);
    int next_cp = T_PAST_ + WSPF_ - 1;
    int cp_k = 0;

    __syncthreads();

    for (int t = 0; t < T_TOT; ++t) {
        // uniform x reads issued early; consumed only after the dot
        float x0 = x_lds[t * 3 + 0];
        float x1 = x_lds[t * 3 + 1];
        float x2 = x_lds[t * 3 + 2];

        // ---- dot: 32 readlane broadcasts + 32 fdot2, 8 accum chains ----
        float a[8] = {bg, 0.f, 0.f, 0.f, 0.f, 0.f, 0.f, 0.f};
        #pragma unroll
        for (int j = 0; j < 32; ++j)
            a[j & 7] = dot2_(w2[j], rl_(pk, 2 * j), a[j & 7]);
        a[1] = fmaf(wih0, x0, a[1]);
        a[2] = fmaf(wih1, x1, a[2]);
        a[3] = fmaf(wih2, x2, a[3]);
        float acc = ((a[0] + a[1]) + (a[2] + a[3]))
                  + ((a[4] + a[5]) + (a[6] + a[7]));

        float e    = __expf(-sc * acc);
        float gval = fmaf(aa, rcp_(1.0f + e), bb);     // sigmoid / tanh
        gates_lds[t & 1][tid] = gval;
        __syncthreads();               // gates(t) visible to all waves

        // ---- update (all waves redundantly, unit `lane`) ----
        float gi = gates_lds[t & 1][0 * H_SZ + lane];
        float gf = gates_lds[t & 1][1 * H_SZ + lane];
        float gg = gates_lds[t & 1][2 * H_SZ + lane];
        float go = gates_lds[t & 1][3 * H_SZ + lane];
        c = fmaf(gf, c, gi * gg);
        float h = go * tanh_(c);

        // pack (h_2j, h_2j+1) on even lanes: neighbor h via DPP (no LDS)
        float hn = dpp_xor1_(h);
        pk = as_i(__builtin_amdgcn_cvt_pkrtz(h, hn));
        // no 2nd barrier: pk is register state; gates double-buffer
        // tolerates <=1-step wave skew

        if (t == next_cp) {            // block-uniform condition
            if (wv == 0) {             // pk holds valid pairs on even lanes
                float p = bpj;
                #pragma unroll
                for (int j = 0; j < 32; ++j) {
                    h2 hp = as_h2(rl_(pk, 2 * j));
                    p = fmaf(wproj_lds[lane * PSTRIDE + 2*j    ], (float)hp.x, p);
                    p = fmaf(wproj_lds[lane * PSTRIDE + 2*j + 1], (float)hp.y, p);
                }
                outb[cp_k * H_SZ + lane] = p;
            }
            next_cp += WSPF_;
            ++cp_k;
        }
    }
}

extern "C" void kernel_launch(void* const* d_in, const int* in_sizes, int n_in,
                              void* d_out, int out_size, void* d_ws, size_t ws_size,
                              hipStream_t stream) {
    const float* wave_input  = (const float*)d_in[0];
    const float* wave_future = (const float*)d_in[1];
    const float* W_ih        = (const float*)d_in[2];
    const float* W_hh        = (const float*)d_in[3];
    const float* b_ih        = (const float*)d_in[4];
    const float* b_hh        = (const float*)d_in[5];
    const float* W_proj      = (const float*)d_in[6];
    const float* b_proj      = (const float*)d_in[7];
    float* out               = (float*)d_out;

    lstm_fused_kernel<<<BATCH, NTHREADS, 0, stream>>>(
        wave_input, wave_future, W_ih, W_hh, b_ih, b_hh, W_proj, b_proj, out);
}